// Round 1
// baseline (1546.111 us; speedup 1.0000x reference)
//
#include <hip/hip_runtime.h>

static constexpr float FILLW = 2.0f;

// Order-preserving float<->uint encoding for atomicMax on floats.
__device__ __forceinline__ unsigned fenc(float f){
    unsigned u = __float_as_uint(f);
    return (u & 0x80000000u) ? ~u : (u | 0x80000000u);
}
__device__ __forceinline__ float fdec(unsigned u){
    unsigned b = (u & 0x80000000u) ? (u & 0x7FFFFFFFu) : ~u;
    return __uint_as_float(b);
}

__global__ void k_init(float* __restrict__ deg, unsigned* __restrict__ agg1,
                       unsigned* __restrict__ agg2, int N, int n1, int n2){
    int j = blockIdx.x * blockDim.x + threadIdx.x;
    if (j < n2) agg2[j] = 0u;       // encoded -NaN: below every real float
    if (j < n1) agg1[j] = 0u;
    if (j < N)  deg[j]  = FILLW;    // self-loop weight pre-seeded
}

__global__ void k_deg(const int* __restrict__ dst, const float* __restrict__ ew,
                      float* __restrict__ deg, int E){
    int e = blockIdx.x * blockDim.x + threadIdx.x;
    if (e < E) atomicAdd(&deg[dst[e]], fmaxf(ew[e], 0.f));
}

__global__ void k_dinv(float* __restrict__ deg, int N){
    int i = blockIdx.x * blockDim.x + threadIdx.x;
    if (i < N) deg[i] = rsqrtf(deg[i]);   // deg >= 2 always (self-loop)
}

__global__ void k_norm(const int* __restrict__ src, const int* __restrict__ dst,
                       const float* __restrict__ ew, const float* __restrict__ dinv,
                       float* __restrict__ norm, int E){
    int e = blockIdx.x * blockDim.x + threadIdx.x;
    if (e < E) norm[e] = dinv[src[e]] * fmaxf(ew[e], 0.f) * dinv[dst[e]];
}

// C[N,F] = A[N,K] * W[K,F]; requires K*F <= 8192; blockDim = 256; 32 rows/block.
__global__ void k_gemm(const float* __restrict__ A, const float* __restrict__ W,
                       float* __restrict__ C, int N, int K, int F){
    __shared__ float Wl[8192];
    for (int i = threadIdx.x; i < K * F; i += 256) Wl[i] = W[i];
    __syncthreads();
    int c     = threadIdx.x & (F - 1);
    int rq    = threadIdx.x / F;       // wave-uniform for F in {64,128}
    int rstep = 256 / F;
    int rbase = blockIdx.x * 32;
    for (int rr = rq; rr < 32; rr += rstep) {
        int r = rbase + rr;
        if (r >= N) return;            // no syncs below: safe
        const float* a = A + (size_t)r * K;
        float acc = 0.f;
        #pragma unroll 8
        for (int k = 0; k < K; ++k) acc = fmaf(a[k], Wl[k * F + c], acc);
        C[(size_t)r * F + c] = acc;
    }
}

// Edge-parallel scatter-max: one thread per (edge,feature). Edges [0,E) are the
// real edges; [E, E+N) are the improved self-loops (weight FILL).
template<int F>
__global__ void k_agg(const int* __restrict__ src, const int* __restrict__ dst,
                      const float* __restrict__ norm, const float* __restrict__ dinv,
                      const float* __restrict__ H, unsigned* __restrict__ agg,
                      int E, int N){
    unsigned t = blockIdx.x * blockDim.x + threadIdx.x;
    unsigned total = (unsigned)(E + N) * F;
    if (t >= total) return;
    int f = t & (F - 1);
    int e = t / F;
    int s, d; float nrm;
    if (e < E) { s = src[e]; d = dst[e]; nrm = norm[e]; }
    else       { s = d = e - E; float di = dinv[s]; nrm = FILLW * di * di; }
    float v = nrm * H[(size_t)s * F + f];
    atomicMax(&agg[(size_t)d * F + f], fenc(v));
}

__global__ void k_dec(const unsigned* __restrict__ agg, const float* __restrict__ b,
                      float* __restrict__ out, int n, int Fm1){
    int j = blockIdx.x * blockDim.x + threadIdx.x;
    if (j < n) out[j] = fdec(agg[j]) + b[j & Fm1];
}

extern "C" void kernel_launch(void* const* d_in, const int* in_sizes, int n_in,
                              void* d_out, int out_size, void* d_ws, size_t ws_size,
                              hipStream_t stream){
    const int E  = in_sizes[2];        // 800000
    const int F1 = in_sizes[7];        // 64
    const int F2 = in_sizes[9];        // 128
    const int IN = in_sizes[6] / F1;   // 128
    const int N  = in_sizes[0] / IN;   // 50000

    const float* W1 = (const float*)d_in[6];
    const float* b1 = (const float*)d_in[7];
    const float* W2 = (const float*)d_in[8];
    const float* b2 = (const float*)d_in[9];

    // Workspace layout (reused across towers; ~55 MB total):
    float*    deg  = (float*)d_ws;                       // N   (deg -> dinv in place)
    float*    norm = deg + N;                            // E
    float*    h1   = norm + E;                           // N*F1
    unsigned* agg1 = (unsigned*)(h1 + (size_t)N * F1);   // N*F1
    float*    h2   = (float*)(agg1 + (size_t)N * F1);    // N*F2
    float*    out1 = (float*)agg1;                       // decoded in place

    for (int t = 0; t < 2; ++t) {
        const float* x  = (const float*)d_in[t * 3 + 0];
        const int*   ei = (const int*)  d_in[t * 3 + 1];
        const float* ew = (const float*)d_in[t * 3 + 2];
        const int* src = ei;
        const int* dst = ei + E;
        float*    gout = (float*)d_out + (size_t)t * N * F2;
        unsigned* agg2 = (unsigned*)gout;   // encode final max in place in d_out

        const int n1 = N * F1, n2 = N * F2;
        k_init<<<(n2 + 255) / 256, 256, 0, stream>>>(deg, agg1, agg2, N, n1, n2);
        k_deg <<<(E + 255) / 256, 256, 0, stream>>>(dst, ew, deg, E);
        k_dinv<<<(N + 255) / 256, 256, 0, stream>>>(deg, N);
        k_norm<<<(E + 255) / 256, 256, 0, stream>>>(src, dst, ew, deg, norm, E);

        // Layer 1: h1 = x @ W1 ; agg1 = segment_max(norm * h1[src], dst)
        k_gemm<<<(N + 31) / 32, 256, 0, stream>>>(x, W1, h1, N, IN, F1);
        {
            long long tot = (long long)(E + N) * F1;
            k_agg<64><<<(unsigned)((tot + 255) / 256), 256, 0, stream>>>(
                src, dst, norm, deg, h1, agg1, E, N);
        }
        k_dec<<<(n1 + 255) / 256, 256, 0, stream>>>(agg1, b1, out1, n1, F1 - 1);

        // Layer 2: h2 = out1 @ W2 ; gout = segment_max(norm * h2[src], dst) + b2
        k_gemm<<<(N + 31) / 32, 256, 0, stream>>>(out1, W2, h2, N, F1, F2);
        {
            long long tot = (long long)(E + N) * F2;
            k_agg<128><<<(unsigned)((tot + 255) / 256), 256, 0, stream>>>(
                src, dst, norm, deg, h2, agg2, E, N);
        }
        k_dec<<<(n2 + 255) / 256, 256, 0, stream>>>(agg2, b2, gout, n2, F2 - 1);
    }
}

// Round 2
// 1005.952 us; speedup vs baseline: 1.5370x; 1.5370x over previous
//
#include <hip/hip_runtime.h>

static constexpr float FILLW = 2.0f;

// ---------- CSR build ----------

__global__ void k_init0(float* __restrict__ deg, int* __restrict__ work, int N){
    int i = blockIdx.x * blockDim.x + threadIdx.x;
    if (i < N) { deg[i] = FILLW; work[i] = 0; }
}

__global__ void k_count(const int* __restrict__ dst, const float* __restrict__ ew,
                        int* __restrict__ work, float* __restrict__ deg, int E){
    int e = blockIdx.x * blockDim.x + threadIdx.x;
    if (e < E) {
        int d = dst[e];
        atomicAdd(&work[d], 1);
        atomicAdd(&deg[d], fmaxf(ew[e], 0.f));
    }
}

// Single-workgroup chunked exclusive scan, in place. blockDim = 1024.
__global__ void k_scan(int* __restrict__ w, int N){
    __shared__ int wsum[17];
    const int tid = threadIdx.x, lane = tid & 63, wv = tid >> 6;
    int carry = 0;
    for (int base = 0; base < N; base += 1024) {
        int i = base + tid;
        int v = (i < N) ? w[i] : 0;
        int s = v;
        #pragma unroll
        for (int off = 1; off < 64; off <<= 1) {
            int t = __shfl_up(s, off);
            if (lane >= off) s += t;
        }
        if (lane == 63) wsum[wv] = s;
        __syncthreads();
        if (tid == 0) {
            int acc = 0;
            for (int k = 0; k < 16; ++k) { int t = wsum[k]; wsum[k] = acc; acc += t; }
            wsum[16] = acc;
        }
        __syncthreads();
        if (i < N) w[i] = carry + wsum[wv] + (s - v);   // exclusive
        carry += wsum[16];
        __syncthreads();   // protect wsum before next chunk
    }
}

__global__ void k_dinv(float* __restrict__ deg, int N){
    int i = blockIdx.x * blockDim.x + threadIdx.x;
    if (i < N) deg[i] = rsqrtf(deg[i]);   // deg >= FILLW = 2 always
}

__global__ void k_fill(const int* __restrict__ src, const int* __restrict__ dst,
                       const float* __restrict__ ew, const float* __restrict__ dinv,
                       int* __restrict__ work, float2* __restrict__ sn, int E){
    int e = blockIdx.x * blockDim.x + threadIdx.x;
    if (e < E) {
        int s = src[e], d = dst[e];
        float nr = dinv[s] * fmaxf(ew[e], 0.f) * dinv[d];
        int p = atomicAdd(&work[d], 1);
        sn[p] = make_float2(__int_as_float(s), nr);
    }
}

// ---------- dense GEMM: C[N,F] = A[N,K]*W[K,F], K*F <= 8192, block 256 ----------
__global__ void k_gemm(const float* __restrict__ A, const float* __restrict__ W,
                       float* __restrict__ C, int N, int K, int F){
    __shared__ float Wl[8192];
    for (int i = threadIdx.x; i < K * F; i += 256) Wl[i] = W[i];
    __syncthreads();
    int c     = threadIdx.x & (F - 1);
    int rq    = threadIdx.x / F;       // wave-uniform for F in {64,128}
    int rstep = 256 / F;
    int rbase = blockIdx.x * 32;
    for (int rr = rq; rr < 32; rr += rstep) {
        int r = rbase + rr;
        if (r >= N) return;            // no syncs below: safe
        const float* a = A + (size_t)r * K;
        float acc = 0.f;
        #pragma unroll 8
        for (int k = 0; k < K; ++k) acc = fmaf(a[k], Wl[k * F + c], acc);
        C[(size_t)r * F + c] = acc;
    }
}

// ---------- CSR gather-max aggregation, bias fused. One wave per node. ----------
// endptr[n] = inclusive prefix (end of segment n); beg = endptr[n-1].
template<int F, int V>   // V = F/64 elements per lane (1 or 2)
__global__ void k_agg_csr(const int* __restrict__ endptr, const float2* __restrict__ sn,
                          const float* __restrict__ dinv, const float* __restrict__ H,
                          const float* __restrict__ bias, float* __restrict__ out, int N){
    const int lane = threadIdx.x & 63, wv = threadIdx.x >> 6;
    int n = blockIdx.x * 4 + wv;
    if (n >= N) return;
    int beg = (n == 0) ? 0 : endptr[n - 1];
    int end = endptr[n];
    float di = dinv[n];
    float self = FILLW * di * di;
    float v0, v1 = 0.f;
    if (V == 1) {
        v0 = self * H[(size_t)n * F + lane];
    } else {
        float2 h = ((const float2*)H)[(size_t)n * (F / 2) + lane];
        v0 = self * h.x; v1 = self * h.y;
    }
    float2 nxt = make_float2(0.f, 0.f);
    if (beg < end) nxt = sn[beg];
    for (int j = beg; j < end; ++j) {
        float2 cur = nxt;
        if (j + 1 < end) nxt = sn[j + 1];           // software prefetch
        int   s  = __float_as_int(cur.x);
        float nr = cur.y;
        if (V == 1) {
            v0 = fmaxf(v0, nr * H[(size_t)s * F + lane]);
        } else {
            float2 h = ((const float2*)H)[(size_t)s * (F / 2) + lane];
            v0 = fmaxf(v0, nr * h.x);
            v1 = fmaxf(v1, nr * h.y);
        }
    }
    if (V == 1) {
        out[(size_t)n * F + lane] = v0 + bias[lane];
    } else {
        float2 b = ((const float2*)bias)[lane];
        ((float2*)out)[(size_t)n * (F / 2) + lane] = make_float2(v0 + b.x, v1 + b.y);
    }
}

extern "C" void kernel_launch(void* const* d_in, const int* in_sizes, int n_in,
                              void* d_out, int out_size, void* d_ws, size_t ws_size,
                              hipStream_t stream){
    const int E  = in_sizes[2];        // 800000
    const int F1 = in_sizes[7];        // 64
    const int F2 = in_sizes[9];        // 128
    const int IN = in_sizes[6] / F1;   // 128
    const int N  = in_sizes[0] / IN;   // 50000

    const float* W1 = (const float*)d_in[6];
    const float* b1 = (const float*)d_in[7];
    const float* W2 = (const float*)d_in[8];
    const float* b2 = (const float*)d_in[9];

    // Workspace layout (~45 MB): deg | work | srcnorm | out1 | h1 (h2 overlays h1)
    float*  deg  = (float*)d_ws;                       // N floats (deg -> dinv in place)
    int*    work = (int*)(deg + N);                    // N ints (cnt -> excl -> incl)
    float2* sn   = (float2*)(work + N);                // E float2
    float*  out1 = (float*)(sn + E);                   // N*F1
    float*  h1   = out1 + (size_t)N * F1;              // N*F1
    float*  h2   = h1;                                 // N*F2 (overlays dead h1 + tail)

    for (int t = 0; t < 2; ++t) {
        const float* x  = (const float*)d_in[t * 3 + 0];
        const int*   ei = (const int*)  d_in[t * 3 + 1];
        const float* ew = (const float*)d_in[t * 3 + 2];
        const int* src = ei;
        const int* dst = ei + E;
        float*    gout = (float*)d_out + (size_t)t * N * F2;

        // CSR build (shared by both layers)
        k_init0<<<(N + 255) / 256, 256, 0, stream>>>(deg, work, N);
        k_count<<<(E + 255) / 256, 256, 0, stream>>>(dst, ew, work, deg, E);
        k_scan <<<1, 1024, 0, stream>>>(work, N);
        k_dinv <<<(N + 255) / 256, 256, 0, stream>>>(deg, N);
        k_fill <<<(E + 255) / 256, 256, 0, stream>>>(src, dst, ew, deg, work, sn, E);

        // Layer 1: h1 = x@W1 ; out1 = segmax(norm*h1[src]) + b1
        k_gemm<<<(N + 31) / 32, 256, 0, stream>>>(x, W1, h1, N, IN, F1);
        k_agg_csr<64, 1><<<(N + 3) / 4, 256, 0, stream>>>(work, sn, deg, h1, b1, out1, N);

        // Layer 2: h2 = out1@W2 ; gout = segmax(norm*h2[src]) + b2
        k_gemm<<<(N + 31) / 32, 256, 0, stream>>>(out1, W2, h2, N, F1, F2);
        k_agg_csr<128, 2><<<(N + 3) / 4, 256, 0, stream>>>(work, sn, deg, h2, b2, gout, N);
    }
}

// Round 3
// 658.523 us; speedup vs baseline: 2.3478x; 1.5276x over previous
//
#include <hip/hip_runtime.h>

static constexpr float FILLW = 2.0f;

// ============================ CSR build ============================

__global__ void k_init(float* __restrict__ deg, int* __restrict__ work, int NG){
    int i = blockIdx.x * 256 + threadIdx.x;
    if (i < NG){ deg[i] = FILLW; work[i] = 0; }
}

__global__ void k_count(const int* __restrict__ dst0, const int* __restrict__ dst1,
                        const float* __restrict__ ew0, const float* __restrict__ ew1,
                        int* __restrict__ work, float* __restrict__ deg,
                        int E, int N, int EB){
    int t = blockIdx.x >= EB;
    int e = (blockIdx.x - t * EB) * 256 + threadIdx.x;
    const int* dst = t ? dst1 : dst0;
    const float* ew = t ? ew1 : ew0;
    if (e < E){
        int d = dst[e] + t * N;
        atomicAdd(&work[d], 1);
        atomicAdd(&deg[d], fmaxf(ew[e], 0.f));
    }
}

// Phase A: per-block exclusive scan of 1024-element segments (per tower).
__global__ void k_scanA(int* __restrict__ work, int* __restrict__ bsum, int N, int SB){
    int t = blockIdx.x / SB, bb = blockIdx.x % SB;
    int base = t * N + bb * 1024;
    int lim  = t * N + N;
    int i0 = base + threadIdx.x * 4;
    int4 v = {0,0,0,0};
    if (i0 + 3 < lim) v = *(const int4*)(work + i0);
    else {
        if (i0     < lim) v.x = work[i0];
        if (i0 + 1 < lim) v.y = work[i0+1];
        if (i0 + 2 < lim) v.z = work[i0+2];
        if (i0 + 3 < lim) v.w = work[i0+3];
    }
    int s = v.x + v.y + v.z + v.w;
    int lane = threadIdx.x & 63, wv = threadIdx.x >> 6;
    int sc = s;
    #pragma unroll
    for (int o = 1; o < 64; o <<= 1){ int u = __shfl_up(sc, o); if (lane >= o) sc += u; }
    __shared__ int ws[4];
    if (lane == 63) ws[wv] = sc;
    __syncthreads();
    int wbase = 0;
    #pragma unroll
    for (int k = 0; k < 4; ++k) if (k < wv) wbase += ws[k];
    int excl = wbase + sc - s;
    int4 o;
    o.x = excl; o.y = o.x + v.x; o.z = o.y + v.y; o.w = o.z + v.z;
    if (i0 + 3 < lim) *(int4*)(work + i0) = o;
    else {
        if (i0     < lim) work[i0]   = o.x;
        if (i0 + 1 < lim) work[i0+1] = o.y;
        if (i0 + 2 < lim) work[i0+2] = o.z;
        if (i0 + 3 < lim) work[i0+3] = o.w;
    }
    if (threadIdx.x == 255) bsum[blockIdx.x] = o.w + v.w;
}

// Phase B: scan block sums, segmented per tower (total <= 256).
__global__ void k_scanB(int* __restrict__ bsum, int total, int SB){
    __shared__ int s[256];
    int i = threadIdx.x;
    s[i] = (i < total) ? bsum[i] : 0;
    __syncthreads();
    if (i == 0){
        int acc = 0;
        for (int k = 0; k < total; ++k){
            if (k % SB == 0) acc = 0;
            int tv = s[k]; s[k] = acc; acc += tv;
        }
    }
    __syncthreads();
    if (i < total) bsum[i] = s[i];
}

// Phase C + rsqrt(deg) fused.
__global__ void k_scanC_dinv(int* __restrict__ work, const int* __restrict__ bsum,
                             float* __restrict__ deg, int N, int SB, int NG){
    int i = blockIdx.x * 256 + threadIdx.x;
    if (i < NG){
        int t = i / N, off = i - t * N;
        work[i] += bsum[t * SB + off / 1024];
        deg[i] = rsqrtf(deg[i]);   // deg >= FILLW always
    }
}

__global__ void k_fill(const int* __restrict__ src0, const int* __restrict__ src1,
                       const int* __restrict__ dst0, const int* __restrict__ dst1,
                       const float* __restrict__ ew0, const float* __restrict__ ew1,
                       const float* __restrict__ dinv, int* __restrict__ work,
                       float2* __restrict__ sn, int E, int N, int EB){
    int t = blockIdx.x >= EB;
    int e = (blockIdx.x - t * EB) * 256 + threadIdx.x;
    const int* src = t ? src1 : src0;
    const int* dst = t ? dst1 : dst0;
    const float* ew = t ? ew1 : ew0;
    if (e < E){
        int s = src[e], d = dst[e];
        float nr = dinv[s + t*N] * fmaxf(ew[e], 0.f) * dinv[d + t*N];
        int p = atomicAdd(&work[d + t*N], 1);
        sn[(size_t)t * E + p] = make_float2(__int_as_float(s), nr);
    }
}

// ======================= register-blocked GEMM =======================
// C[N,F] = A[N,K] * W[K,F]. Block: 256 thr, tile TR rows x F cols,
// micro-tile 8x8/thread. A chunk staged transposed [k][row] in LDS (dbuf),
// W fully in LDS. All LDS reads are b128 with <=2-way bank aliasing (free).
template<int F, int K, int TR, int KC>
__global__ void __launch_bounds__(256) k_gemm(const float* __restrict__ A0,
        const float* __restrict__ A1, const float* __restrict__ W,
        float* __restrict__ C0, float* __restrict__ C1, int N, int BPT){
    constexpr int NCH = K / KC;
    constexpr int TRp = TR + 4;            // k-plane stride (floats), 16B-mult
    constexpr int CG  = F / 8;             // col groups
    constexpr int LPT = TR * KC / 1024;    // float4 stage loads per thread
    __shared__ float Ws[K * F];
    __shared__ float As[2][KC * TRp];
    const int tid = threadIdx.x;
    const int t = blockIdx.x >= BPT;
    const int b = blockIdx.x - t * BPT;
    const float* __restrict__ A = t ? A1 : A0;
    float* __restrict__ C = t ? C1 : C0;
    const int rb = b * TR;
    for (int i = tid; i < K * F / 4; i += 256)
        ((float4*)Ws)[i] = ((const float4*)W)[i];
    const int tx = tid % CG, ty = tid / CG;
    const int c0 = tx * 8, r0 = ty * 8;

    float acc[8][8];
    #pragma unroll
    for (int i = 0; i < 8; ++i)
        #pragma unroll
        for (int j = 0; j < 8; ++j) acc[i][j] = 0.f;

    float4 st[LPT];
    auto gload = [&](int kc){
        #pragma unroll
        for (int l2 = 0; l2 < LPT; ++l2){
            int l = l2 * 256 + tid;
            int r = l / (KC / 4);
            int kk = (l % (KC / 4)) * 4;
            int ar = rb + r; if (ar >= N) ar = N - 1;
            st[l2] = *(const float4*)(A + (size_t)ar * K + kc * KC + kk);
        }
    };
    auto swrite = [&](int buf){
        float* p = &As[buf][0];
        #pragma unroll
        for (int l2 = 0; l2 < LPT; ++l2){
            int l = l2 * 256 + tid;
            int r = l / (KC / 4);
            int kk = (l % (KC / 4)) * 4;
            p[(kk+0)*TRp + r] = st[l2].x;
            p[(kk+1)*TRp + r] = st[l2].y;
            p[(kk+2)*TRp + r] = st[l2].z;
            p[(kk+3)*TRp + r] = st[l2].w;
        }
    };

    gload(0); swrite(0);
    __syncthreads();
    for (int kc = 0; kc < NCH; ++kc){
        if (kc + 1 < NCH) gload(kc + 1);           // issue early; vmcnt waits later
        const float* Ab = &As[kc & 1][0];
        #pragma unroll
        for (int j = 0; j < KC; ++j){
            const float* wrow = &Ws[(kc * KC + j) * F + c0];
            float4 w0 = *(const float4*)(wrow);
            float4 w1 = *(const float4*)(wrow + 4);
            float4 a0 = *(const float4*)(Ab + j * TRp + r0);
            float4 a1 = *(const float4*)(Ab + j * TRp + r0 + 4);
            float av[8] = {a0.x,a0.y,a0.z,a0.w,a1.x,a1.y,a1.z,a1.w};
            float wv[8] = {w0.x,w0.y,w0.z,w0.w,w1.x,w1.y,w1.z,w1.w};
            #pragma unroll
            for (int rr = 0; rr < 8; ++rr)
                #pragma unroll
                for (int cc = 0; cc < 8; ++cc)
                    acc[rr][cc] = fmaf(av[rr], wv[cc], acc[rr][cc]);
        }
        if (kc + 1 < NCH){ swrite((kc + 1) & 1); __syncthreads(); }
    }
    #pragma unroll
    for (int rr = 0; rr < 8; ++rr){
        int row = rb + r0 + rr;
        if (row < N){
            float4 o0 = {acc[rr][0], acc[rr][1], acc[rr][2], acc[rr][3]};
            float4 o1 = {acc[rr][4], acc[rr][5], acc[rr][6], acc[rr][7]};
            *(float4*)(C + (size_t)row * F + c0)     = o0;
            *(float4*)(C + (size_t)row * F + c0 + 4) = o1;
        }
    }
}

// =================== CSR gather-max aggregation ===================
template<int F, int V>   // V = F/64 floats per lane
__global__ void __launch_bounds__(256) k_agg(const int* __restrict__ work,
        const float2* __restrict__ sn, const float* __restrict__ deg,
        const float* __restrict__ H0, const float* __restrict__ H1,
        const float* __restrict__ bias, float* __restrict__ O0, float* __restrict__ O1,
        int N, int BPT, int E){
    const int t = blockIdx.x >= BPT;
    const int lane = threadIdx.x & 63, wv = threadIdx.x >> 6;
    int n = (blockIdx.x - t * BPT) * 4 + wv;
    if (n >= N) return;
    const int* endptr = work + t * N;
    const float2* snt = sn + (size_t)t * E;
    const float* dinv = deg + t * N;
    const float* H = t ? H1 : H0;
    float* O = t ? O1 : O0;

    int beg = (n == 0) ? 0 : endptr[n - 1];
    int end = endptr[n];
    float di = dinv[n];
    float self = FILLW * di * di;
    float v0, v1 = 0.f;
    if (V == 1) {
        v0 = self * H[(size_t)n * F + lane];
    } else {
        float2 h = ((const float2*)H)[(size_t)n * (F/2) + lane];
        v0 = self * h.x; v1 = self * h.y;
    }
    float2 nxt = make_float2(0.f, 0.f);
    if (beg < end) nxt = snt[beg];
    for (int j = beg; j < end; ++j){
        float2 cur = nxt;
        if (j + 1 < end) nxt = snt[j + 1];
        int   s  = __float_as_int(cur.x);
        float nr = cur.y;
        if (V == 1) {
            v0 = fmaxf(v0, nr * H[(size_t)s * F + lane]);
        } else {
            float2 h = ((const float2*)H)[(size_t)s * (F/2) + lane];
            v0 = fmaxf(v0, nr * h.x);
            v1 = fmaxf(v1, nr * h.y);
        }
    }
    if (V == 1) {
        O[(size_t)n * F + lane] = v0 + bias[lane];
    } else {
        float2 bb = ((const float2*)bias)[lane];
        ((float2*)O)[(size_t)n * (F/2) + lane] = make_float2(v0 + bb.x, v1 + bb.y);
    }
}

// ============================== host ==============================

extern "C" void kernel_launch(void* const* d_in, const int* in_sizes, int n_in,
                              void* d_out, int out_size, void* d_ws, size_t ws_size,
                              hipStream_t stream){
    const int E  = in_sizes[2];        // 800000
    const int F1 = in_sizes[7];        // 64
    const int F2 = in_sizes[9];        // 128
    const int IN = in_sizes[6] / F1;   // 128
    const int N  = in_sizes[0] / IN;   // 50000
    const int SB = (N + 1023) / 1024;

    const float* W1 = (const float*)d_in[6];
    const float* b1 = (const float*)d_in[7];
    const float* W2 = (const float*)d_in[8];
    const float* b2 = (const float*)d_in[9];

    auto need = [&](int G){
        return (size_t)G * E * 8 + (size_t)G * N * F1 * 4 + (size_t)G * N * F2 * 4
             + (size_t)G * N * 8 + 4096;
    };
    int G = (ws_size >= need(2)) ? 2 : 1;

    // layout: sn | out1 | hbuf | deg | work | bsum
    float2* sn   = (float2*)d_ws;
    float*  out1 = (float*)(sn + (size_t)G * E);
    float*  hbuf = out1 + (size_t)G * N * F1;
    float*  deg  = hbuf + (size_t)G * N * F2;
    int*    work = (int*)(deg + G * N);
    int*    bsum = work + G * N;

    const int NG = G * N;
    const int EB = (E + 255) / 256;
    const int BPT1 = (N + 255) / 256;   // gemm1: TR=256
    const int BPT2 = (N + 127) / 128;   // gemm2: TR=128
    const int ABT  = (N + 3) / 4;       // agg blocks per tower

    for (int it = 0; it < 2; it += G){
        int t0 = it, t1 = (G == 2) ? it + 1 : it;
        const float* x0 = (const float*)d_in[t0*3], * x1 = (const float*)d_in[t1*3];
        const int* ei0 = (const int*)d_in[t0*3+1], * ei1 = (const int*)d_in[t1*3+1];
        const float* ew0 = (const float*)d_in[t0*3+2], * ew1 = (const float*)d_in[t1*3+2];
        const int* src0 = ei0, * dst0 = ei0 + E;
        const int* src1 = ei1, * dst1 = ei1 + E;
        float* h1_0 = hbuf,                  * h1_1 = hbuf + (size_t)(G-1) * N * F1;
        float* h2_0 = hbuf,                  * h2_1 = hbuf + (size_t)(G-1) * N * F2;
        float* o1_0 = out1,                  * o1_1 = out1 + (size_t)(G-1) * N * F1;
        float* go0  = (float*)d_out + (size_t)t0 * N * F2;
        float* go1  = (float*)d_out + (size_t)t1 * N * F2;

        k_init <<<(NG + 255)/256, 256, 0, stream>>>(deg, work, NG);
        k_count<<<G * EB, 256, 0, stream>>>(dst0, dst1, ew0, ew1, work, deg, E, N, EB);
        k_scanA<<<G * SB, 256, 0, stream>>>(work, bsum, N, SB);
        k_scanB<<<1, 256, 0, stream>>>(bsum, G * SB, SB);
        k_scanC_dinv<<<(NG + 255)/256, 256, 0, stream>>>(work, bsum, deg, N, SB, NG);
        k_fill <<<G * EB, 256, 0, stream>>>(src0, src1, dst0, dst1, ew0, ew1,
                                            deg, work, sn, E, N, EB);

        k_gemm<64,128,256,8><<<G * BPT1, 256, 0, stream>>>(x0, x1, W1, h1_0, h1_1, N, BPT1);
        k_agg<64,1><<<G * ABT, 256, 0, stream>>>(work, sn, deg, h1_0, h1_1, b1,
                                                 o1_0, o1_1, N, ABT, E);
        k_gemm<128,64,128,16><<<G * BPT2, 256, 0, stream>>>(o1_0, o1_1, W2, h2_0, h2_1, N, BPT2);
        k_agg<128,2><<<G * ABT, 256, 0, stream>>>(work, sn, deg, h2_0, h2_1, b2,
                                                  go0, go1, N, ABT, E);
    }
}

// Round 4
// 566.110 us; speedup vs baseline: 2.7311x; 1.1632x over previous
//
#include <hip/hip_runtime.h>

static constexpr float FILLW = 2.0f;

// ============================ scan (3-phase) ============================

// Phase A: per-block exclusive scan of 1024-element segments (per tower).
__global__ void k_scanA(int* __restrict__ work, int* __restrict__ bsum, int N, int SB){
    int t = blockIdx.x / SB, bb = blockIdx.x % SB;
    int base = t * N + bb * 1024;
    int lim  = t * N + N;
    int i0 = base + threadIdx.x * 4;
    int4 v = {0,0,0,0};
    if (i0 + 3 < lim) v = *(const int4*)(work + i0);
    else {
        if (i0     < lim) v.x = work[i0];
        if (i0 + 1 < lim) v.y = work[i0+1];
        if (i0 + 2 < lim) v.z = work[i0+2];
        if (i0 + 3 < lim) v.w = work[i0+3];
    }
    int s = v.x + v.y + v.z + v.w;
    int lane = threadIdx.x & 63, wv = threadIdx.x >> 6;
    int sc = s;
    #pragma unroll
    for (int o = 1; o < 64; o <<= 1){ int u = __shfl_up(sc, o); if (lane >= o) sc += u; }
    __shared__ int ws[4];
    if (lane == 63) ws[wv] = sc;
    __syncthreads();
    int wbase = 0;
    #pragma unroll
    for (int k = 0; k < 4; ++k) if (k < wv) wbase += ws[k];
    int excl = wbase + sc - s;
    int4 o;
    o.x = excl; o.y = o.x + v.x; o.z = o.y + v.y; o.w = o.z + v.z;
    if (i0 + 3 < lim) *(int4*)(work + i0) = o;
    else {
        if (i0     < lim) work[i0]   = o.x;
        if (i0 + 1 < lim) work[i0+1] = o.y;
        if (i0 + 2 < lim) work[i0+2] = o.z;
        if (i0 + 3 < lim) work[i0+3] = o.w;
    }
    if (threadIdx.x == 255) bsum[blockIdx.x] = o.w + v.w;
}

// Phase B: scan block sums, segmented per tower (total <= 256).
__global__ void k_scanB(int* __restrict__ bsum, int total, int SB){
    __shared__ int s[256];
    int i = threadIdx.x;
    s[i] = (i < total) ? bsum[i] : 0;
    __syncthreads();
    if (i == 0){
        int acc = 0;
        for (int k = 0; k < total; ++k){
            if (k % SB == 0) acc = 0;
            int tv = s[k]; s[k] = acc; acc += tv;
        }
    }
    __syncthreads();
    if (i < total) bsum[i] = s[i];
}

// Phase C: add block bases -> final per-tower EXCLUSIVE offsets.
__global__ void k_scanC(int* __restrict__ work, const int* __restrict__ bsum,
                        int N, int SB, int GN){
    int i = blockIdx.x * 256 + threadIdx.x;
    if (i < GN){
        int t = i >= N, off = i - t * N;
        work[i] += bsum[t * SB + off / 1024];
    }
}

// ======================= register-blocked GEMM tile =======================
// C[N,F] = A[N,K] * W[K,F] (optionally row-scaled by dv[row]). 256 threads,
// TR rows x F cols, 8x8 micro-tile/thread, A staged transposed in LDS (dbuf).
template<int F, int K, int TR, int KC, bool SCALE>
__device__ __forceinline__ void gemm_tile(const float* __restrict__ A,
        const float* __restrict__ W, float* __restrict__ C,
        const float* __restrict__ dv, int rb, int N,
        float* __restrict__ Ws, float* __restrict__ As){
    constexpr int NCH = K / KC;
    constexpr int TRp = TR + 4;
    constexpr int CG  = F / 8;
    constexpr int LPT = TR * KC / 1024;
    const int tid = threadIdx.x;
    for (int i = tid; i < K * F / 4; i += 256)
        ((float4*)Ws)[i] = ((const float4*)W)[i];
    const int tx = tid % CG, ty = tid / CG;
    const int c0 = tx * 8, r0 = ty * 8;

    float acc[8][8];
    #pragma unroll
    for (int i = 0; i < 8; ++i)
        #pragma unroll
        for (int j = 0; j < 8; ++j) acc[i][j] = 0.f;

    float4 st[LPT];
    auto gload = [&](int kc){
        #pragma unroll
        for (int l2 = 0; l2 < LPT; ++l2){
            int l = l2 * 256 + tid;
            int r = l / (KC / 4);
            int kk = (l % (KC / 4)) * 4;
            int ar = rb + r; if (ar >= N) ar = N - 1;
            st[l2] = *(const float4*)(A + (size_t)ar * K + kc * KC + kk);
        }
    };
    auto swrite = [&](int buf){
        float* p = As + buf * (KC * TRp);
        #pragma unroll
        for (int l2 = 0; l2 < LPT; ++l2){
            int l = l2 * 256 + tid;
            int r = l / (KC / 4);
            int kk = (l % (KC / 4)) * 4;
            p[(kk+0)*TRp + r] = st[l2].x;
            p[(kk+1)*TRp + r] = st[l2].y;
            p[(kk+2)*TRp + r] = st[l2].z;
            p[(kk+3)*TRp + r] = st[l2].w;
        }
    };

    gload(0); swrite(0);
    __syncthreads();
    for (int kc = 0; kc < NCH; ++kc){
        if (kc + 1 < NCH) gload(kc + 1);
        const float* Ab = As + (kc & 1) * (KC * TRp);
        #pragma unroll
        for (int j = 0; j < KC; ++j){
            const float* wrow = Ws + (kc * KC + j) * F + c0;
            float4 w0 = *(const float4*)(wrow);
            float4 w1 = *(const float4*)(wrow + 4);
            float4 a0 = *(const float4*)(Ab + j * TRp + r0);
            float4 a1 = *(const float4*)(Ab + j * TRp + r0 + 4);
            float av[8] = {a0.x,a0.y,a0.z,a0.w,a1.x,a1.y,a1.z,a1.w};
            float wv[8] = {w0.x,w0.y,w0.z,w0.w,w1.x,w1.y,w1.z,w1.w};
            #pragma unroll
            for (int rr = 0; rr < 8; ++rr)
                #pragma unroll
                for (int cc = 0; cc < 8; ++cc)
                    acc[rr][cc] = fmaf(av[rr], wv[cc], acc[rr][cc]);
        }
        if (kc + 1 < NCH){ swrite((kc + 1) & 1); __syncthreads(); }
    }
    #pragma unroll
    for (int rr = 0; rr < 8; ++rr){
        int row = rb + r0 + rr;
        if (row < N){
            float scv = 1.0f;
            if constexpr (SCALE) scv = dv[row];
            float4 o0 = {acc[rr][0]*scv, acc[rr][1]*scv, acc[rr][2]*scv, acc[rr][3]*scv};
            float4 o1 = {acc[rr][4]*scv, acc[rr][5]*scv, acc[rr][6]*scv, acc[rr][7]*scv};
            *(float4*)(C + (size_t)row * F + c0)     = o0;
            *(float4*)(C + (size_t)row * F + c0 + 4) = o1;
        }
    }
}

// ========== fused: GEMM1 (blocks [0,GB)) + dst histogram w/ rank ==========
__global__ void __launch_bounds__(256) k_cg1(const float* __restrict__ x0,
        const float* __restrict__ x1, const float* __restrict__ W1,
        float* __restrict__ h0, float* __restrict__ h1,
        const int* __restrict__ dst0, const int* __restrict__ dst1,
        int* __restrict__ cnt, int* __restrict__ rank,
        int N, int E, int BPT, int GB, int EB){
    if ((int)blockIdx.x < GB){
        __shared__ float Ws[64 * 128];
        __shared__ float As[2 * 8 * 260];
        int t  = (int)blockIdx.x >= BPT;
        int rb = ((int)blockIdx.x - t * BPT) * 256;
        gemm_tile<64,128,256,8,false>(t ? x1 : x0, W1, t ? h1 : h0,
                                      nullptr, rb, N, Ws, As);
        return;
    }
    int c = (int)blockIdx.x - GB;
    int t = c >= EB;
    int e = (c - t * EB) * 256 + threadIdx.x;
    if (e < E){
        int d = (t ? dst1 : dst0)[e];
        rank[(size_t)t * E + e] = atomicAdd(&cnt[t * N + d], 1);
    }
}

// =============== fill (no atomics: offset[d] + saved rank) ===============
__global__ void k_fill(const int* __restrict__ src0, const int* __restrict__ src1,
                       const int* __restrict__ dst0, const int* __restrict__ dst1,
                       const float* __restrict__ ew0, const float* __restrict__ ew1,
                       const int* __restrict__ work, const int* __restrict__ rank,
                       float2* __restrict__ sn, int N, int E, int EB){
    int t = (int)blockIdx.x >= EB;
    int e = ((int)blockIdx.x - t * EB) * 256 + threadIdx.x;
    if (e < E){
        int s = (t ? src1 : src0)[e];
        int d = (t ? dst1 : dst0)[e];
        float w = fmaxf((t ? ew1 : ew0)[e], 0.f);
        int pos = work[t * N + d] + rank[(size_t)t * E + e];
        sn[(size_t)t * E + pos] = make_float2(__int_as_float(s), w);
    }
}

// ==== deg from CSR (no atomics) -> dinv; scale h1 rows by dinv in place ====
__global__ void __launch_bounds__(256) k_degscale(const int* __restrict__ work,
        const float2* __restrict__ sn, float* __restrict__ dinv,
        float* __restrict__ hbuf, int N, int E, int GN, int NF2){
    int g = (int)blockIdx.x * 256 + threadIdx.x;
    float dv = 0.f;
    if (g < GN){
        int t = g >= N;
        int n = g - t * N;
        int beg = work[g];
        int end = (n == N - 1) ? E : work[g + 1];
        const float2* s = sn + (size_t)t * E;
        float acc = FILLW;
        for (int j = beg; j < end; ++j) acc += s[j].y;
        dv = rsqrtf(acc);        // acc >= FILLW always
        dinv[g] = dv;
    }
    // cooperative: wave scales its 64 nodes' h1 rows (F1 = 64 floats each)
    int lane  = threadIdx.x & 63;
    int wbase = (int)blockIdx.x * 256 + (threadIdx.x & ~63);
    for (int r = 0; r < 64; ++r){
        int gr = wbase + r;
        float scv = __shfl(dv, r);
        if (gr < GN){
            int t = gr >= N;
            int n = gr - t * N;
            float* row = hbuf + (size_t)t * NF2 + (size_t)n * 64;
            row[lane] *= scv;
        }
    }
}

// ================== standalone GEMM2 with dinv row-scale ==================
__global__ void __launch_bounds__(256) k_gemm2(const float* __restrict__ A0,
        const float* __restrict__ A1, const float* __restrict__ W,
        float* __restrict__ C0, float* __restrict__ C1,
        const float* __restrict__ dinv, int N, int BPT){
    __shared__ float Ws[64 * 128];
    __shared__ float As[2 * 16 * 132];
    int t  = (int)blockIdx.x >= BPT;
    int rb = ((int)blockIdx.x - t * BPT) * 128;
    gemm_tile<128,64,128,16,true>(t ? A1 : A0, W, t ? C1 : C0,
                                  dinv + t * N, rb, N, Ws, As);
}

// ============== CSR gather-max: out = dinv[n]*max(...) + b ==============
template<int F, int V>   // V = F/64 floats per lane
__global__ void __launch_bounds__(256) k_agg(const int* __restrict__ work,
        const float2* __restrict__ sn, const float* __restrict__ dinv,
        const float* __restrict__ H0, const float* __restrict__ H1,
        const float* __restrict__ bias, float* __restrict__ O0, float* __restrict__ O1,
        int N, int E, int BPT){
    const int t = (int)blockIdx.x >= BPT;
    const int lane = threadIdx.x & 63, wv = threadIdx.x >> 6;
    int n = ((int)blockIdx.x - t * BPT) * 4 + wv;
    if (n >= N) return;
    int g = t * N + n;
    int beg = work[g];
    int end = (n == N - 1) ? E : work[g + 1];
    const float2* st = sn + (size_t)t * E;
    const float* H = t ? H1 : H0;
    float* O = t ? O1 : O0;
    float di = dinv[g];
    float v0, v1 = 0.f;
    if (V == 1) {
        v0 = FILLW * H[(size_t)n * F + lane];           // self: 2*H'[n]
    } else {
        float2 h = ((const float2*)H)[(size_t)n * (F/2) + lane];
        v0 = FILLW * h.x; v1 = FILLW * h.y;
    }
    float2 nxt = make_float2(0.f, 0.f);
    if (beg < end) nxt = st[beg];
    for (int j = beg; j < end; ++j){
        float2 cur = nxt;
        if (j + 1 < end) nxt = st[j + 1];
        int   s = __float_as_int(cur.x);
        float w = cur.y;
        if (V == 1) {
            v0 = fmaxf(v0, w * H[(size_t)s * F + lane]);
        } else {
            float2 h = ((const float2*)H)[(size_t)s * (F/2) + lane];
            v0 = fmaxf(v0, w * h.x);
            v1 = fmaxf(v1, w * h.y);
        }
    }
    if (V == 1) {
        O[(size_t)n * F + lane] = di * v0 + bias[lane];
    } else {
        float2 bb = ((const float2*)bias)[lane];
        ((float2*)O)[(size_t)n * (F/2) + lane] = make_float2(di*v0 + bb.x, di*v1 + bb.y);
    }
}

// ============================== host ==============================

extern "C" void kernel_launch(void* const* d_in, const int* in_sizes, int n_in,
                              void* d_out, int out_size, void* d_ws, size_t ws_size,
                              hipStream_t stream){
    const int E  = in_sizes[2];        // 800000
    const int F1 = in_sizes[7];        // 64
    const int F2 = in_sizes[9];        // 128
    const int IN = in_sizes[6] / F1;   // 128
    const int N  = in_sizes[0] / IN;   // 50000
    const int SB = (N + 1023) / 1024;

    const float* W1 = (const float*)d_in[6];
    const float* b1 = (const float*)d_in[7];
    const float* W2 = (const float*)d_in[8];
    const float* b2 = (const float*)d_in[9];

    auto need = [&](int G){
        return (size_t)G * E * 8 + (size_t)G * N * F1 * 4 + (size_t)G * N * F2 * 4
             + (size_t)G * N * 8 + 4096;
    };
    const int G = (ws_size >= need(2)) ? 2 : 1;

    // layout: sn | hbuf | out1 (rank overlays out1) | dinv | work | bsum
    float2* sn   = (float2*)d_ws;                      // G*E float2
    float*  hbuf = (float*)(sn + (size_t)G * E);       // G*N*F2
    float*  out1 = hbuf + (size_t)G * N * F2;          // G*N*F1
    int*    rank = (int*)out1;                          // G*E ints (dead before agg1)
    float*  dinv = out1 + (size_t)G * N * F1;          // G*N
    int*    work = (int*)(dinv + G * N);               // G*N
    int*    bsum = work + G * N;

    const int GN   = G * N;
    const int EB   = (E + 255) / 256;
    const int BPT1 = (N + 255) / 256;
    const int BPT2 = (N + 127) / 128;
    const int ABT  = (N + 3) / 4;
    const int GB   = G * BPT1;

    for (int it = 0; it < 2; it += G){
        int t0 = it, t1 = (G == 2) ? it + 1 : it;
        const float* x0 = (const float*)d_in[t0*3], * x1 = (const float*)d_in[t1*3];
        const int* ei0 = (const int*)d_in[t0*3+1], * ei1 = (const int*)d_in[t1*3+1];
        const float* ew0 = (const float*)d_in[t0*3+2], * ew1 = (const float*)d_in[t1*3+2];
        const int* src0 = ei0, * dst0 = ei0 + E;
        const int* src1 = ei1, * dst1 = ei1 + E;
        float* h_0 = hbuf, * h_1 = hbuf + (size_t)(G-1) * N * F2;  // h1 then h2 (same buf)
        float* o1_0 = out1, * o1_1 = out1 + (size_t)(G-1) * N * F1;
        float* go0 = (float*)d_out + (size_t)t0 * N * F2;
        float* go1 = (float*)d_out + (size_t)t1 * N * F2;

        hipMemsetAsync(work, 0, (size_t)GN * sizeof(int), stream);
        k_cg1<<<GB + G * EB, 256, 0, stream>>>(x0, x1, W1, h_0, h_1,
                                               dst0, dst1, work, rank, N, E, BPT1, GB, EB);
        k_scanA<<<G * SB, 256, 0, stream>>>(work, bsum, N, SB);
        k_scanB<<<1, 256, 0, stream>>>(bsum, G * SB, SB);
        k_scanC<<<(GN + 255) / 256, 256, 0, stream>>>(work, bsum, N, SB, GN);
        k_fill<<<G * EB, 256, 0, stream>>>(src0, src1, dst0, dst1, ew0, ew1,
                                           work, rank, sn, N, E, EB);
        k_degscale<<<(GN + 255) / 256, 256, 0, stream>>>(work, sn, dinv, hbuf,
                                                         N, E, GN, N * F2);
        k_agg<64,1><<<G * ABT, 256, 0, stream>>>(work, sn, dinv, h_0, h_1, b1,
                                                 o1_0, o1_1, N, E, ABT);
        k_gemm2<<<G * BPT2, 256, 0, stream>>>(o1_0, o1_1, W2, h_0, h_1, dinv, N, BPT2);
        k_agg<128,2><<<G * ABT, 256, 0, stream>>>(work, sn, dinv, h_0, h_1, b2,
                                                  go0, go1, N, E, ABT);
    }
}

// Round 5
// 511.895 us; speedup vs baseline: 3.0204x; 1.1059x over previous
//
#include <hip/hip_runtime.h>
#include <hip/hip_fp16.h>

static constexpr float FILLW = 2.0f;

// ============================ scan (3-phase) ============================

__global__ void k_scanA(int* __restrict__ work, int* __restrict__ bsum, int N, int SB){
    int t = blockIdx.x / SB, bb = blockIdx.x % SB;
    int base = t * N + bb * 1024;
    int lim  = t * N + N;
    int i0 = base + threadIdx.x * 4;
    int4 v = {0,0,0,0};
    if (i0 + 3 < lim) v = *(const int4*)(work + i0);
    else {
        if (i0     < lim) v.x = work[i0];
        if (i0 + 1 < lim) v.y = work[i0+1];
        if (i0 + 2 < lim) v.z = work[i0+2];
        if (i0 + 3 < lim) v.w = work[i0+3];
    }
    int s = v.x + v.y + v.z + v.w;
    int lane = threadIdx.x & 63, wv = threadIdx.x >> 6;
    int sc = s;
    #pragma unroll
    for (int o = 1; o < 64; o <<= 1){ int u = __shfl_up(sc, o); if (lane >= o) sc += u; }
    __shared__ int ws[4];
    if (lane == 63) ws[wv] = sc;
    __syncthreads();
    int wbase = 0;
    #pragma unroll
    for (int k = 0; k < 4; ++k) if (k < wv) wbase += ws[k];
    int excl = wbase + sc - s;
    int4 o;
    o.x = excl; o.y = o.x + v.x; o.z = o.y + v.y; o.w = o.z + v.z;
    if (i0 + 3 < lim) *(int4*)(work + i0) = o;
    else {
        if (i0     < lim) work[i0]   = o.x;
        if (i0 + 1 < lim) work[i0+1] = o.y;
        if (i0 + 2 < lim) work[i0+2] = o.z;
        if (i0 + 3 < lim) work[i0+3] = o.w;
    }
    if (threadIdx.x == 255) bsum[blockIdx.x] = o.w + v.w;
}

__global__ void k_scanB(int* __restrict__ bsum, int total, int SB){
    __shared__ int s[256];
    int i = threadIdx.x;
    s[i] = (i < total) ? bsum[i] : 0;
    __syncthreads();
    if (i == 0){
        int acc = 0;
        for (int k = 0; k < total; ++k){
            if (k % SB == 0) acc = 0;
            int tv = s[k]; s[k] = acc; acc += tv;
        }
    }
    __syncthreads();
    if (i < total) bsum[i] = s[i];
}

__global__ void k_scanC(int* __restrict__ work, const int* __restrict__ bsum,
                        int N, int SB, int GN){
    int i = blockIdx.x * 256 + threadIdx.x;
    if (i < GN){
        int t = i >= N, off = i - t * N;
        work[i] += bsum[t * SB + off / 1024];
    }
}

// ======================= register-blocked GEMM tile =======================
// C[N,F] = A[N,K] * W[K,F], optional row scale dv[row], OutT in {float,__half}.
template<int F, int K, int TR, int KC, bool SCALE, typename OutT>
__device__ __forceinline__ void gemm_tile(const float* __restrict__ A,
        const float* __restrict__ W, OutT* __restrict__ C,
        const float* __restrict__ dv, int rb, int N,
        float* __restrict__ Ws, float* __restrict__ As){
    constexpr int NCH = K / KC;
    constexpr int TRp = TR + 4;
    constexpr int CG  = F / 8;
    constexpr int LPT = TR * KC / 1024;
    const int tid = threadIdx.x;
    for (int i = tid; i < K * F / 4; i += 256)
        ((float4*)Ws)[i] = ((const float4*)W)[i];
    const int tx = tid % CG, ty = tid / CG;
    const int c0 = tx * 8, r0 = ty * 8;

    float acc[8][8];
    #pragma unroll
    for (int i = 0; i < 8; ++i)
        #pragma unroll
        for (int j = 0; j < 8; ++j) acc[i][j] = 0.f;

    float4 st[LPT];
    auto gload = [&](int kc){
        #pragma unroll
        for (int l2 = 0; l2 < LPT; ++l2){
            int l = l2 * 256 + tid;
            int r = l / (KC / 4);
            int kk = (l % (KC / 4)) * 4;
            int ar = rb + r; if (ar >= N) ar = N - 1;
            st[l2] = *(const float4*)(A + (size_t)ar * K + kc * KC + kk);
        }
    };
    auto swrite = [&](int buf){
        float* p = As + buf * (KC * TRp);
        #pragma unroll
        for (int l2 = 0; l2 < LPT; ++l2){
            int l = l2 * 256 + tid;
            int r = l / (KC / 4);
            int kk = (l % (KC / 4)) * 4;
            p[(kk+0)*TRp + r] = st[l2].x;
            p[(kk+1)*TRp + r] = st[l2].y;
            p[(kk+2)*TRp + r] = st[l2].z;
            p[(kk+3)*TRp + r] = st[l2].w;
        }
    };

    gload(0); swrite(0);
    __syncthreads();
    for (int kc = 0; kc < NCH; ++kc){
        if (kc + 1 < NCH) gload(kc + 1);
        const float* Ab = As + (kc & 1) * (KC * TRp);
        #pragma unroll
        for (int j = 0; j < KC; ++j){
            const float* wrow = Ws + (kc * KC + j) * F + c0;
            float4 w0 = *(const float4*)(wrow);
            float4 w1 = *(const float4*)(wrow + 4);
            float4 a0 = *(const float4*)(Ab + j * TRp + r0);
            float4 a1 = *(const float4*)(Ab + j * TRp + r0 + 4);
            float av[8] = {a0.x,a0.y,a0.z,a0.w,a1.x,a1.y,a1.z,a1.w};
            float wvv[8] = {w0.x,w0.y,w0.z,w0.w,w1.x,w1.y,w1.z,w1.w};
            #pragma unroll
            for (int rr = 0; rr < 8; ++rr)
                #pragma unroll
                for (int cc = 0; cc < 8; ++cc)
                    acc[rr][cc] = fmaf(av[rr], wvv[cc], acc[rr][cc]);
        }
        if (kc + 1 < NCH){ swrite((kc + 1) & 1); __syncthreads(); }
    }
    #pragma unroll
    for (int rr = 0; rr < 8; ++rr){
        int row = rb + r0 + rr;
        if (row < N){
            float scv = 1.0f;
            if constexpr (SCALE) scv = dv[row];
            if constexpr (sizeof(OutT) == 2){
                __half2 o2[4];
                #pragma unroll
                for (int q = 0; q < 4; ++q)
                    o2[q] = __floats2half2_rn(acc[rr][2*q]*scv, acc[rr][2*q+1]*scv);
                *(float4*)((__half*)C + (size_t)row * F + c0) = *(float4*)o2;
            } else {
                float4 o0 = {acc[rr][0]*scv, acc[rr][1]*scv, acc[rr][2]*scv, acc[rr][3]*scv};
                float4 o1 = {acc[rr][4]*scv, acc[rr][5]*scv, acc[rr][6]*scv, acc[rr][7]*scv};
                *(float4*)((float*)C + (size_t)row * F + c0)     = o0;
                *(float4*)((float*)C + (size_t)row * F + c0 + 4) = o1;
            }
        }
    }
}

// ========== fused: GEMM1 (fp16 out) + dst histogram w/ rank ==========
__global__ void __launch_bounds__(256) k_cg1(const float* __restrict__ x0,
        const float* __restrict__ x1, const float* __restrict__ W1,
        __half* __restrict__ h0, __half* __restrict__ h1,
        const int* __restrict__ dst0, const int* __restrict__ dst1,
        int* __restrict__ cnt, int* __restrict__ rank,
        int N, int E, int BPT, int GB, int EB){
    if ((int)blockIdx.x < GB){
        __shared__ float Ws[64 * 128];
        __shared__ float As[2 * 8 * 260];
        int t  = (int)blockIdx.x >= BPT;
        int rb = ((int)blockIdx.x - t * BPT) * 256;
        gemm_tile<64,128,256,8,false,__half>(t ? x1 : x0, W1, t ? h1 : h0,
                                             nullptr, rb, N, Ws, As);
        return;
    }
    int c = (int)blockIdx.x - GB;
    int t = c >= EB;
    int e = (c - t * EB) * 256 + threadIdx.x;
    if (e < E){
        int d = (t ? dst1 : dst0)[e];
        rank[(size_t)t * E + e] = atomicAdd(&cnt[t * N + d], 1);
    }
}

// =============== fill (no atomics: offset[d] + saved rank) ===============
__global__ void k_fill(const int* __restrict__ src0, const int* __restrict__ src1,
                       const int* __restrict__ dst0, const int* __restrict__ dst1,
                       const float* __restrict__ ew0, const float* __restrict__ ew1,
                       const int* __restrict__ work, const int* __restrict__ rank,
                       float2* __restrict__ sn, int N, int E, int EB){
    int t = (int)blockIdx.x >= EB;
    int e = ((int)blockIdx.x - t * EB) * 256 + threadIdx.x;
    if (e < E){
        int s = (t ? src1 : src0)[e];
        int d = (t ? dst1 : dst0)[e];
        float w = fmaxf((t ? ew1 : ew0)[e], 0.f);
        int pos = work[t * N + d] + rank[(size_t)t * E + e];
        sn[(size_t)t * E + pos] = make_float2(__int_as_float(s), w);
    }
}

// ==== dinv = rsqrt(FILLW + CSR segment-sum); prescale h1 rows (fp16) ====
__global__ void __launch_bounds__(256) k_degdinv(const int* __restrict__ work,
        const float2* __restrict__ sn, float* __restrict__ dinv,
        __half* __restrict__ h1buf, int N, int E, int GN){
    int g = (int)blockIdx.x * 256 + threadIdx.x;
    float dv = 0.f;
    if (g < GN){
        int t = g >= N;
        int n = g - t * N;
        int beg = work[g];
        int end = (n == N - 1) ? E : work[g + 1];
        const float2* s = sn + (size_t)t * E;
        float acc = FILLW;
        for (int j = beg; j < end; ++j) acc += s[j].y;
        dv = rsqrtf(acc);
        dinv[g] = dv;
    }
    int lane  = threadIdx.x & 63;
    int wbase = (int)blockIdx.x * 256 + (threadIdx.x & ~63);
    for (int r = 0; r < 64; ++r){
        int gr = wbase + r;
        float scv = __shfl(dv, r);
        if (gr < GN){
            __half* row = h1buf + (size_t)gr * 64;   // g-indexed layout: tower-contiguous
            row[lane] = __float2half(__half2float(row[lane]) * scv);
        }
    }
}

// ================== GEMM2: fp32 in, dinv-prescaled fp16 out ==================
__global__ void __launch_bounds__(256) k_gemm2(const float* __restrict__ A0,
        const float* __restrict__ A1, const float* __restrict__ W,
        __half* __restrict__ C0, __half* __restrict__ C1,
        const float* __restrict__ dinv, int N, int BPT){
    __shared__ float Ws[64 * 128];
    __shared__ float As[2 * 16 * 132];
    int t  = (int)blockIdx.x >= BPT;
    int rb = ((int)blockIdx.x - t * BPT) * 128;
    gemm_tile<128,64,128,16,true,__half>(t ? A1 : A0, W, t ? C1 : C0,
                                         dinv + t * N, rb, N, Ws, As);
}

// ===== CSR gather-max over prescaled fp16 H: out = dinv[n]*max(...) + b =====
template<int F, int V>   // V = F/64 values per lane
__global__ void __launch_bounds__(256) k_agg(const int* __restrict__ work,
        const float2* __restrict__ sn, const float* __restrict__ dinv,
        const __half* __restrict__ H0, const __half* __restrict__ H1,
        const float* __restrict__ bias, float* __restrict__ O0, float* __restrict__ O1,
        int N, int E, int BPT){
    const int t = (int)blockIdx.x >= BPT;
    const int lane = threadIdx.x & 63, wv = threadIdx.x >> 6;
    int n = ((int)blockIdx.x - t * BPT) * 4 + wv;
    if (n >= N) return;
    int g = t * N + n;
    int beg = work[g];
    int end = (n == N - 1) ? E : work[g + 1];
    const float2* st = sn + (size_t)t * E;
    const __half* H = t ? H1 : H0;
    float* O = t ? O1 : O0;
    float di = dinv[g];
    float v0, v1 = 0.f;
    if (V == 1) {
        v0 = FILLW * __half2float(H[(size_t)n * F + lane]);
    } else {
        float2 h = __half22float2(((const __half2*)H)[(size_t)n * (F/2) + lane]);
        v0 = FILLW * h.x; v1 = FILLW * h.y;
    }
    int j = beg;
    for (; j + 1 < end; j += 2){
        float2 ea = st[j];
        float2 eb = st[j + 1];
        int sa = __float_as_int(ea.x);
        int sb = __float_as_int(eb.x);
        if (V == 1) {
            float ha = __half2float(H[(size_t)sa * F + lane]);
            float hb = __half2float(H[(size_t)sb * F + lane]);
            v0 = fmaxf(v0, ea.y * ha);
            v0 = fmaxf(v0, eb.y * hb);
        } else {
            float2 ha = __half22float2(((const __half2*)H)[(size_t)sa * (F/2) + lane]);
            float2 hb = __half22float2(((const __half2*)H)[(size_t)sb * (F/2) + lane]);
            v0 = fmaxf(v0, ea.y * ha.x); v1 = fmaxf(v1, ea.y * ha.y);
            v0 = fmaxf(v0, eb.y * hb.x); v1 = fmaxf(v1, eb.y * hb.y);
        }
    }
    if (j < end){
        float2 ea = st[j];
        int sa = __float_as_int(ea.x);
        if (V == 1) {
            v0 = fmaxf(v0, ea.y * __half2float(H[(size_t)sa * F + lane]));
        } else {
            float2 ha = __half22float2(((const __half2*)H)[(size_t)sa * (F/2) + lane]);
            v0 = fmaxf(v0, ea.y * ha.x); v1 = fmaxf(v1, ea.y * ha.y);
        }
    }
    if (V == 1) {
        O[(size_t)n * F + lane] = di * v0 + bias[lane];
    } else {
        float2 bb = ((const float2*)bias)[lane];
        ((float2*)O)[(size_t)n * (F/2) + lane] = make_float2(di*v0 + bb.x, di*v1 + bb.y);
    }
}

// ============================== host ==============================

extern "C" void kernel_launch(void* const* d_in, const int* in_sizes, int n_in,
                              void* d_out, int out_size, void* d_ws, size_t ws_size,
                              hipStream_t stream){
    const int E  = in_sizes[2];        // 800000
    const int F1 = in_sizes[7];        // 64
    const int F2 = in_sizes[9];        // 128
    const int IN = in_sizes[6] / F1;   // 128
    const int N  = in_sizes[0] / IN;   // 50000
    const int SB = (N + 1023) / 1024;

    const float* W1 = (const float*)d_in[6];
    const float* b1 = (const float*)d_in[7];
    const float* W2 = (const float*)d_in[8];
    const float* b2 = (const float*)d_in[9];

    auto need = [&](int G){
        return (size_t)G * E * 8              // sn
             + (size_t)G * N * F2 * 2         // hbuf (fp16)
             + (size_t)G * N * F1 * 4         // out1 (rank overlays)
             + (size_t)G * N * 8 + 4096;      // dinv + work + bsum
    };
    const int G = (ws_size >= need(2)) ? 2 : 1;

    float2* sn   = (float2*)d_ws;                        // G*E float2
    __half* hbuf = (__half*)(sn + (size_t)G * E);        // G*N*F2 halves
    float*  out1 = (float*)(hbuf + (size_t)G * N * F2);  // G*N*F1 floats
    int*    rank = (int*)out1;                           // G*E ints (dead before agg1)
    float*  dinv = out1 + (size_t)G * N * F1;            // G*N
    int*    work = (int*)(dinv + G * N);                 // G*N
    int*    bsum = work + G * N;

    const int GN   = G * N;
    const int EB   = (E + 255) / 256;
    const int BPT1 = (N + 255) / 256;
    const int BPT2 = (N + 127) / 128;
    const int ABT  = (N + 3) / 4;
    const int GB   = G * BPT1;

    for (int it = 0; it < 2; it += G){
        int t0 = it, t1 = (G == 2) ? it + 1 : it;
        const float* x0 = (const float*)d_in[t0*3], * x1 = (const float*)d_in[t1*3];
        const int* ei0 = (const int*)d_in[t0*3+1], * ei1 = (const int*)d_in[t1*3+1];
        const float* ew0 = (const float*)d_in[t0*3+2], * ew1 = (const float*)d_in[t1*3+2];
        const int* src0 = ei0, * dst0 = ei0 + E;
        const int* src1 = ei1, * dst1 = ei1 + E;
        // h1: tower-contiguous at hbuf (g*64); h2: hbuf + t*N*F2 (h1 dead by then)
        __half* h1_0 = hbuf,  * h1_1 = hbuf + (size_t)(G-1) * N * F1;
        __half* h2_0 = hbuf,  * h2_1 = hbuf + (size_t)(G-1) * N * F2;
        float* o1_0 = out1, * o1_1 = out1 + (size_t)(G-1) * N * F1;
        float* go0 = (float*)d_out + (size_t)t0 * N * F2;
        float* go1 = (float*)d_out + (size_t)t1 * N * F2;

        hipMemsetAsync(work, 0, (size_t)GN * sizeof(int), stream);
        k_cg1<<<GB + G * EB, 256, 0, stream>>>(x0, x1, W1, h1_0, h1_1,
                                               dst0, dst1, work, rank, N, E, BPT1, GB, EB);
        k_scanA<<<G * SB, 256, 0, stream>>>(work, bsum, N, SB);
        k_scanB<<<1, 256, 0, stream>>>(bsum, G * SB, SB);
        k_scanC<<<(GN + 255) / 256, 256, 0, stream>>>(work, bsum, N, SB, GN);
        k_fill<<<G * EB, 256, 0, stream>>>(src0, src1, dst0, dst1, ew0, ew1,
                                           work, rank, sn, N, E, EB);
        k_degdinv<<<(GN + 255) / 256, 256, 0, stream>>>(work, sn, dinv, hbuf, N, E, GN);
        k_agg<64,1><<<G * ABT, 256, 0, stream>>>(work, sn, dinv, h1_0, h1_1, b1,
                                                 o1_0, o1_1, N, E, ABT);
        k_gemm2<<<G * BPT2, 256, 0, stream>>>(o1_0, o1_1, W2, h2_0, h2_1, dinv, N, BPT2);
        k_agg<128,2><<<G * ABT, 256, 0, stream>>>(work, sn, dinv, h2_0, h2_1, b2,
                                                  go0, go1, N, E, ABT);
    }
}

// Round 6
// 430.207 us; speedup vs baseline: 3.5939x; 1.1899x over previous
//
#include <hip/hip_runtime.h>
#include <hip/hip_fp16.h>

static constexpr float FILLW = 2.0f;
static constexpr int PADB = 16;   // ints per histogram bin -> one 64B line per bin

// ============================ scan (3-phase) ============================

// Phase A: scan 1024 bins/block from padded histogram -> compact excl offsets.
__global__ void k_scanA(const int* __restrict__ cntPad, int* __restrict__ woff,
                        int* __restrict__ bsum, int N, int SB){
    int t = blockIdx.x / SB, bb = blockIdx.x % SB;
    int base = bb * 1024 + threadIdx.x * 4;
    const int* cp = cntPad + (size_t)t * N * PADB;
    int4 v = {0,0,0,0};
    if (base     < N) v.x = cp[(size_t)(base    ) * PADB];
    if (base + 1 < N) v.y = cp[(size_t)(base + 1) * PADB];
    if (base + 2 < N) v.z = cp[(size_t)(base + 2) * PADB];
    if (base + 3 < N) v.w = cp[(size_t)(base + 3) * PADB];
    int s = v.x + v.y + v.z + v.w;
    int lane = threadIdx.x & 63, wv = threadIdx.x >> 6;
    int sc = s;
    #pragma unroll
    for (int o = 1; o < 64; o <<= 1){ int u = __shfl_up(sc, o); if (lane >= o) sc += u; }
    __shared__ int ws[4];
    if (lane == 63) ws[wv] = sc;
    __syncthreads();
    int wbase = 0;
    #pragma unroll
    for (int k = 0; k < 4; ++k) if (k < wv) wbase += ws[k];
    int excl = wbase + sc - s;
    int4 o;
    o.x = excl; o.y = o.x + v.x; o.z = o.y + v.y; o.w = o.z + v.z;
    int* wo = woff + t * N;
    if (base     < N) wo[base]     = o.x;
    if (base + 1 < N) wo[base + 1] = o.y;
    if (base + 2 < N) wo[base + 2] = o.z;
    if (base + 3 < N) wo[base + 3] = o.w;
    if (threadIdx.x == 255) bsum[blockIdx.x] = o.w + v.w;
}

__global__ void k_scanB(int* __restrict__ bsum, int total, int SB){
    __shared__ int s[256];
    int i = threadIdx.x;
    s[i] = (i < total) ? bsum[i] : 0;
    __syncthreads();
    if (i == 0){
        int acc = 0;
        for (int k = 0; k < total; ++k){
            if (k % SB == 0) acc = 0;
            int tv = s[k]; s[k] = acc; acc += tv;
        }
    }
    __syncthreads();
    if (i < total) bsum[i] = s[i];
}

__global__ void k_scanC(int* __restrict__ woff, const int* __restrict__ bsum,
                        int N, int SB, int GN){
    int i = blockIdx.x * 256 + threadIdx.x;
    if (i < GN){
        int t = i >= N, off = i - t * N;
        woff[i] += bsum[t * SB + off / 1024];
    }
}

// ======================= register-blocked GEMM tile =======================
template<int F, int K, int TR, int KC, bool SCALE, typename OutT>
__device__ __forceinline__ void gemm_tile(const float* __restrict__ A,
        const float* __restrict__ W, OutT* __restrict__ C,
        const float* __restrict__ dv, int rb, int N,
        float* __restrict__ Ws, float* __restrict__ As){
    constexpr int NCH = K / KC;
    constexpr int TRp = TR + 4;
    constexpr int CG  = F / 8;
    constexpr int LPT = TR * KC / 1024;
    const int tid = threadIdx.x;
    for (int i = tid; i < K * F / 4; i += 256)
        ((float4*)Ws)[i] = ((const float4*)W)[i];
    const int tx = tid % CG, ty = tid / CG;
    const int c0 = tx * 8, r0 = ty * 8;

    float acc[8][8];
    #pragma unroll
    for (int i = 0; i < 8; ++i)
        #pragma unroll
        for (int j = 0; j < 8; ++j) acc[i][j] = 0.f;

    float4 st[LPT];
    auto gload = [&](int kc){
        #pragma unroll
        for (int l2 = 0; l2 < LPT; ++l2){
            int l = l2 * 256 + tid;
            int r = l / (KC / 4);
            int kk = (l % (KC / 4)) * 4;
            int ar = rb + r; if (ar >= N) ar = N - 1;
            st[l2] = *(const float4*)(A + (size_t)ar * K + kc * KC + kk);
        }
    };
    auto swrite = [&](int buf){
        float* p = As + buf * (KC * TRp);
        #pragma unroll
        for (int l2 = 0; l2 < LPT; ++l2){
            int l = l2 * 256 + tid;
            int r = l / (KC / 4);
            int kk = (l % (KC / 4)) * 4;
            p[(kk+0)*TRp + r] = st[l2].x;
            p[(kk+1)*TRp + r] = st[l2].y;
            p[(kk+2)*TRp + r] = st[l2].z;
            p[(kk+3)*TRp + r] = st[l2].w;
        }
    };

    gload(0); swrite(0);
    __syncthreads();
    for (int kc = 0; kc < NCH; ++kc){
        if (kc + 1 < NCH) gload(kc + 1);
        const float* Ab = As + (kc & 1) * (KC * TRp);
        #pragma unroll
        for (int j = 0; j < KC; ++j){
            const float* wrow = Ws + (kc * KC + j) * F + c0;
            float4 w0 = *(const float4*)(wrow);
            float4 w1 = *(const float4*)(wrow + 4);
            float4 a0 = *(const float4*)(Ab + j * TRp + r0);
            float4 a1 = *(const float4*)(Ab + j * TRp + r0 + 4);
            float av[8] = {a0.x,a0.y,a0.z,a0.w,a1.x,a1.y,a1.z,a1.w};
            float wvv[8] = {w0.x,w0.y,w0.z,w0.w,w1.x,w1.y,w1.z,w1.w};
            #pragma unroll
            for (int rr = 0; rr < 8; ++rr)
                #pragma unroll
                for (int cc = 0; cc < 8; ++cc)
                    acc[rr][cc] = fmaf(av[rr], wvv[cc], acc[rr][cc]);
        }
        if (kc + 1 < NCH){ swrite((kc + 1) & 1); __syncthreads(); }
    }
    #pragma unroll
    for (int rr = 0; rr < 8; ++rr){
        int row = rb + r0 + rr;
        if (row < N){
            float scv = 1.0f;
            if constexpr (SCALE) scv = dv[row];
            if constexpr (sizeof(OutT) == 2){
                __half2 o2[4];
                #pragma unroll
                for (int q = 0; q < 4; ++q)
                    o2[q] = __floats2half2_rn(acc[rr][2*q]*scv, acc[rr][2*q+1]*scv);
                *(float4*)((__half*)C + (size_t)row * F + c0) = *(float4*)o2;
            } else {
                float4 o0 = {acc[rr][0]*scv, acc[rr][1]*scv, acc[rr][2]*scv, acc[rr][3]*scv};
                float4 o1 = {acc[rr][4]*scv, acc[rr][5]*scv, acc[rr][6]*scv, acc[rr][7]*scv};
                *(float4*)((float*)C + (size_t)row * F + c0)     = o0;
                *(float4*)((float*)C + (size_t)row * F + c0 + 4) = o1;
            }
        }
    }
}

// ===== fused: GEMM1 (fp16 out) + dst histogram (padded bins) w/ rank =====
__global__ void __launch_bounds__(256) k_cg1(const float* __restrict__ x0,
        const float* __restrict__ x1, const float* __restrict__ W1,
        __half* __restrict__ h0, __half* __restrict__ h1,
        const int* __restrict__ dst0, const int* __restrict__ dst1,
        int* __restrict__ cntPad, int* __restrict__ rank,
        int N, int E, int BPT, int GB, int EB){
    if ((int)blockIdx.x < GB){
        __shared__ float Ws[64 * 128];
        __shared__ float As[2 * 8 * 260];
        int t  = (int)blockIdx.x >= BPT;
        int rb = ((int)blockIdx.x - t * BPT) * 256;
        gemm_tile<64,128,256,8,false,__half>(t ? x1 : x0, W1, t ? h1 : h0,
                                             nullptr, rb, N, Ws, As);
        return;
    }
    int c = (int)blockIdx.x - GB;
    int t = c >= EB;
    int e = (c - t * EB) * 256 + threadIdx.x;
    if (e < E){
        int d = (t ? dst1 : dst0)[e];
        rank[(size_t)t * E + e] = atomicAdd(&cntPad[(size_t)(t * N + d) * PADB], 1);
    }
}

// =============== fill (no atomics: offset[d] + saved rank) ===============
__global__ void k_fill(const int* __restrict__ src0, const int* __restrict__ src1,
                       const int* __restrict__ dst0, const int* __restrict__ dst1,
                       const float* __restrict__ ew0, const float* __restrict__ ew1,
                       const int* __restrict__ woff, const int* __restrict__ rank,
                       float2* __restrict__ sn, int N, int E, int EB){
    int t = (int)blockIdx.x >= EB;
    int e = ((int)blockIdx.x - t * EB) * 256 + threadIdx.x;
    if (e < E){
        int s = (t ? src1 : src0)[e];
        int d = (t ? dst1 : dst0)[e];
        float w = fmaxf((t ? ew1 : ew0)[e], 0.f);
        int pos = woff[t * N + d] + rank[(size_t)t * E + e];
        sn[(size_t)t * E + pos] = make_float2(__int_as_float(s), w);
    }
}

// ==== dinv = rsqrt(FILLW + CSR segment-sum); prescale h1 rows (fp16) ====
__global__ void __launch_bounds__(256) k_degdinv(const int* __restrict__ woff,
        const float2* __restrict__ sn, float* __restrict__ dinv,
        __half* __restrict__ h1buf, int N, int E, int GN){
    int g = (int)blockIdx.x * 256 + threadIdx.x;
    float dv = 0.f;
    if (g < GN){
        int t = g >= N;
        int n = g - t * N;
        int beg = woff[g];
        int end = (n == N - 1) ? E : woff[g + 1];
        const float2* s = sn + (size_t)t * E;
        float acc = FILLW;
        for (int j = beg; j < end; ++j) acc += s[j].y;
        dv = rsqrtf(acc);
        dinv[g] = dv;
    }
    int lane  = threadIdx.x & 63;
    int wbase = (int)blockIdx.x * 256 + (threadIdx.x & ~63);
    for (int r = 0; r < 64; ++r){
        int gr = wbase + r;
        float scv = __shfl(dv, r);
        if (gr < GN){
            __half* row = h1buf + (size_t)gr * 64;
            row[lane] = __float2half(__half2float(row[lane]) * scv);
        }
    }
}

// ================== GEMM2: fp32 in, dinv-prescaled fp16 out ==================
__global__ void __launch_bounds__(256) k_gemm2(const float* __restrict__ A0,
        const float* __restrict__ A1, const float* __restrict__ W,
        __half* __restrict__ C0, __half* __restrict__ C1,
        const float* __restrict__ dinv, int N, int BPT){
    __shared__ float Ws[64 * 128];
    __shared__ float As[2 * 16 * 132];
    int t  = (int)blockIdx.x >= BPT;
    int rb = ((int)blockIdx.x - t * BPT) * 128;
    gemm_tile<128,64,128,16,true,__half>(t ? A1 : A0, W, t ? C1 : C0,
                                         dinv + t * N, rb, N, Ws, As);
}

// ===== CSR gather-max: coalesced edge-record load + shfl broadcast + deep unroll =====
template<int F, int V, int UNR>   // V = F/64 values per lane
__global__ void __launch_bounds__(256) k_agg(const int* __restrict__ woff,
        const float2* __restrict__ sn, const float* __restrict__ dinv,
        const __half* __restrict__ H0, const __half* __restrict__ H1,
        const float* __restrict__ bias, float* __restrict__ O0, float* __restrict__ O1,
        int N, int E, int BPT){
    const int t = (int)blockIdx.x >= BPT;
    const int lane = threadIdx.x & 63, wv = threadIdx.x >> 6;
    int n = ((int)blockIdx.x - t * BPT) * 4 + wv;
    if (n >= N) return;
    int g = t * N + n;
    int beg = woff[g];
    int end = (n == N - 1) ? E : woff[g + 1];
    int cnt = end - beg;
    const float2* st = sn + (size_t)t * E;
    const __half* H = t ? H1 : H0;
    float* O = t ? O1 : O0;
    float di = dinv[g];
    float v0, v1 = 0.f;
    if (V == 1) {
        v0 = FILLW * __half2float(H[(size_t)n * F + lane]);
    } else {
        float2 h = __half22float2(((const __half2*)H)[(size_t)n * (F/2) + lane]);
        v0 = FILLW * h.x; v1 = FILLW * h.y;
    }
    for (int base = 0; base < cnt; base += 64){
        int m = cnt - base; if (m > 64) m = 64;
        float2 er = make_float2(0.f, 0.f);
        if (lane < m) er = st[beg + base + lane];     // ONE coalesced load: 64 records
        int   es = __float_as_int(er.x);
        float ew = er.y;
        int j = 0;
        for (; j + UNR <= m; j += UNR){
            int ss[UNR]; float ww[UNR];
            #pragma unroll
            for (int q = 0; q < UNR; ++q){ ss[q] = __shfl(es, j + q); ww[q] = __shfl(ew, j + q); }
            if (V == 1){
                float hh[UNR];
                #pragma unroll
                for (int q = 0; q < UNR; ++q)
                    hh[q] = __half2float(H[(size_t)ss[q] * F + lane]);   // UNR independent gathers
                #pragma unroll
                for (int q = 0; q < UNR; ++q) v0 = fmaxf(v0, ww[q] * hh[q]);
            } else {
                float2 hh[UNR];
                #pragma unroll
                for (int q = 0; q < UNR; ++q)
                    hh[q] = __half22float2(((const __half2*)H)[(size_t)ss[q] * (F/2) + lane]);
                #pragma unroll
                for (int q = 0; q < UNR; ++q){
                    v0 = fmaxf(v0, ww[q] * hh[q].x);
                    v1 = fmaxf(v1, ww[q] * hh[q].y);
                }
            }
        }
        for (; j < m; ++j){
            int s = __shfl(es, j); float w = __shfl(ew, j);
            if (V == 1){
                v0 = fmaxf(v0, w * __half2float(H[(size_t)s * F + lane]));
            } else {
                float2 h = __half22float2(((const __half2*)H)[(size_t)s * (F/2) + lane]);
                v0 = fmaxf(v0, w * h.x); v1 = fmaxf(v1, w * h.y);
            }
        }
    }
    if (V == 1) {
        O[(size_t)n * F + lane] = di * v0 + bias[lane];
    } else {
        float2 bb = ((const float2*)bias)[lane];
        ((float2*)O)[(size_t)n * (F/2) + lane] = make_float2(di*v0 + bb.x, di*v1 + bb.y);
    }
}

// ============================== host ==============================

extern "C" void kernel_launch(void* const* d_in, const int* in_sizes, int n_in,
                              void* d_out, int out_size, void* d_ws, size_t ws_size,
                              hipStream_t stream){
    const int E  = in_sizes[2];        // 800000
    const int F1 = in_sizes[7];        // 64
    const int F2 = in_sizes[9];        // 128
    const int IN = in_sizes[6] / F1;   // 128
    const int N  = in_sizes[0] / IN;   // 50000
    const int SB = (N + 1023) / 1024;

    const float* W1 = (const float*)d_in[6];
    const float* b1 = (const float*)d_in[7];
    const float* W2 = (const float*)d_in[8];
    const float* b2 = (const float*)d_in[9];

    auto need = [&](int G){
        return (size_t)G * E * 8              // sn
             + (size_t)G * N * F2 * 2         // hbuf (fp16)
             + (size_t)G * N * F1 * 4         // out1 (rank overlays)
             + (size_t)G * N * 8              // dinv + woff
             + (size_t)G * N * PADB * 4       // padded histogram
             + 8192;                          // bsum + slack
    };
    const int G = (ws_size >= need(2)) ? 2 : 1;

    float2* sn     = (float2*)d_ws;                        // G*E float2
    __half* hbuf   = (__half*)(sn + (size_t)G * E);        // G*N*F2 halves
    float*  out1   = (float*)(hbuf + (size_t)G * N * F2);  // G*N*F1 floats
    int*    rank   = (int*)out1;                           // G*E ints (dead before agg1)
    float*  dinv   = out1 + (size_t)G * N * F1;            // G*N
    int*    woff   = (int*)(dinv + G * N);                 // G*N
    int*    bsum   = woff + G * N;                         // <=256
    int*    cntPad = bsum + 512;                           // G*N*PADB

    const int GN   = G * N;
    const int EB   = (E + 255) / 256;
    const int BPT1 = (N + 255) / 256;
    const int BPT2 = (N + 127) / 128;
    const int ABT  = (N + 3) / 4;
    const int GB   = G * BPT1;

    for (int it = 0; it < 2; it += G){
        int t0 = it, t1 = (G == 2) ? it + 1 : it;
        const float* x0 = (const float*)d_in[t0*3], * x1 = (const float*)d_in[t1*3];
        const int* ei0 = (const int*)d_in[t0*3+1], * ei1 = (const int*)d_in[t1*3+1];
        const float* ew0 = (const float*)d_in[t0*3+2], * ew1 = (const float*)d_in[t1*3+2];
        const int* src0 = ei0, * dst0 = ei0 + E;
        const int* src1 = ei1, * dst1 = ei1 + E;
        __half* h1_0 = hbuf,  * h1_1 = hbuf + (size_t)(G-1) * N * F1;
        __half* h2_0 = hbuf,  * h2_1 = hbuf + (size_t)(G-1) * N * F2;
        float* o1_0 = out1, * o1_1 = out1 + (size_t)(G-1) * N * F1;
        float* go0 = (float*)d_out + (size_t)t0 * N * F2;
        float* go1 = (float*)d_out + (size_t)t1 * N * F2;

        hipMemsetAsync(cntPad, 0, (size_t)GN * PADB * sizeof(int), stream);
        k_cg1<<<GB + G * EB, 256, 0, stream>>>(x0, x1, W1, h1_0, h1_1,
                                               dst0, dst1, cntPad, rank, N, E, BPT1, GB, EB);
        k_scanA<<<G * SB, 256, 0, stream>>>(cntPad, woff, bsum, N, SB);
        k_scanB<<<1, 256, 0, stream>>>(bsum, G * SB, SB);
        k_scanC<<<(GN + 255) / 256, 256, 0, stream>>>(woff, bsum, N, SB, GN);
        k_fill<<<G * EB, 256, 0, stream>>>(src0, src1, dst0, dst1, ew0, ew1,
                                           woff, rank, sn, N, E, EB);
        k_degdinv<<<(GN + 255) / 256, 256, 0, stream>>>(woff, sn, dinv, hbuf, N, E, GN);
        k_agg<64,1,8><<<G * ABT, 256, 0, stream>>>(woff, sn, dinv, h1_0, h1_1, b1,
                                                   o1_0, o1_1, N, E, ABT);
        k_gemm2<<<G * BPT2, 256, 0, stream>>>(o1_0, o1_1, W2, h2_0, h2_1, dinv, N, BPT2);
        k_agg<128,2,8><<<G * ABT, 256, 0, stream>>>(woff, sn, dinv, h2_0, h2_1, b2,
                                                    go0, go1, N, E, ABT);
    }
}